// Round 1
// baseline (1775.353 us; speedup 1.0000x reference)
//
#include <hip/hip_runtime.h>
#include <stdint.h>

// RNG_MODE: 0 = partitionable threefry (64-bit iota counter, bits = y0^y1)  [modern JAX default]
//           1 = partitionable, bits = y0
//           2 = original (pre-partitionable) scheme: count iota split in halves
#define RNG_MODE 0

#define NH  12
#define SEQ 1024
#define DM  768
#define DK  64
#define NS  32
#define NELEM (2u * NH * SEQ * SEQ)   // 25165824
#define HALFN (NELEM / 2u)            // 12582912

// ---- threefry2x32-20, exact JAX round/key-injection schedule ----
#define TF1(r) { x0 += x1; x1 = (x1 << (r)) | (x1 >> (32 - (r))); x1 ^= x0; }
#define TF4(a,b,c,d) TF1(a) TF1(b) TF1(c) TF1(d)
#define TF_BODY(K0, K1) do { \
  uint32_t ks2_ = (K0) ^ (K1) ^ 0x1BD11BDAu; \
  x0 += (K0); x1 += (K1); \
  TF4(13,15,26,6) \
  x0 += (K1); x1 += ks2_ + 1u; \
  TF4(17,29,16,24) \
  x0 += ks2_; x1 += (K0) + 2u; \
  TF4(13,15,26,6) \
  x0 += (K0); x1 += (K1) + 3u; \
  TF4(17,29,16,24) \
  x0 += (K1); x1 += ks2_ + 4u; \
  TF4(13,15,26,6) \
  x0 += ks2_; x1 += (K0) + 5u; \
} while (0)

struct KeysT { uint32_t a[NS]; uint32_t b[NS]; };

constexpr KeysT make_keys() {
  KeysT K{};
#if RNG_MODE == 2
  uint32_t outv[2 * NS] = {};
  for (int i = 0; i < NS; ++i) {
    uint32_t x0 = (uint32_t)i, x1 = (uint32_t)(NS + i);
    TF_BODY(0u, 42u);                       // key(42) = (0, 42)
    outv[i] = x0; outv[NS + i] = x1;
  }
  for (int s = 0; s < NS; ++s) { K.a[s] = outv[2 * s]; K.b[s] = outv[2 * s + 1]; }
#else
  for (int s = 0; s < NS; ++s) {            // foldlike split: counter (0, s)
    uint32_t x0 = 0u, x1 = (uint32_t)s;
    TF_BODY(0u, 42u);
    K.a[s] = x0; K.b[s] = x1;
  }
#endif
  return K;
}

__constant__ KeysT d_keys = make_keys();

__device__ __forceinline__ uint32_t draw_bits(uint32_t k0, uint32_t k1, uint32_t j) {
#if RNG_MODE == 2
  uint32_t x0 = (j < HALFN) ? j : (j - HALFN);
  uint32_t x1 = x0 + HALFN;
  TF_BODY(k0, k1);
  return (j < HALFN) ? x0 : x1;
#else
  uint32_t x0 = 0u, x1 = j;                 // 64-bit iota: hi=0 (size < 2^32), lo=j
  TF_BODY(k0, k1);
#if RNG_MODE == 0
  return x0 ^ x1;
#else
  return x0;
#endif
#endif
}

// ---- QKV projection: out[r,c] = x[r,:] . W[c,:] + bias[c], scattered to [b,h,s,dk] ----
__global__ __launch_bounds__(256)
void gemm_qkv(const float* __restrict__ x,
              const float* __restrict__ Wq, const float* __restrict__ bq,
              const float* __restrict__ Wk, const float* __restrict__ bk,
              const float* __restrict__ Wv, const float* __restrict__ bv,
              float* __restrict__ Qb, float* __restrict__ Kb, float* __restrict__ Vb) {
  const int z = blockIdx.z;
  const float* W    = (z == 0) ? Wq : (z == 1) ? Wk : Wv;
  const float* bias = (z == 0) ? bq : (z == 1) ? bk : bv;
  float* outb       = (z == 0) ? Qb : (z == 1) ? Kb : Vb;
  const int row0 = blockIdx.y * 64;
  const int col0 = blockIdx.x * 64;
  __shared__ float As[64][17];
  __shared__ float Bs[16][65];
  const int t = threadIdx.x;
  const int tx = t & 15, ty = t >> 4;
  float acc[4][4] = {};
  for (int k0 = 0; k0 < DM; k0 += 16) {
    #pragma unroll
    for (int i = 0; i < 4; ++i) {
      int idx = t + i * 256;
      int ar = idx >> 4, ac = idx & 15;
      As[ar][ac] = x[(row0 + ar) * DM + k0 + ac];
      int kk = idx & 15, c = idx >> 4;
      Bs[kk][c] = W[(col0 + c) * DM + k0 + kk];
    }
    __syncthreads();
    #pragma unroll
    for (int kk = 0; kk < 16; ++kk) {
      float a[4], bb[4];
      #pragma unroll
      for (int i = 0; i < 4; ++i) a[i] = As[ty * 4 + i][kk];
      #pragma unroll
      for (int j = 0; j < 4; ++j) bb[j] = Bs[kk][tx * 4 + j];
      #pragma unroll
      for (int i = 0; i < 4; ++i)
        #pragma unroll
        for (int j = 0; j < 4; ++j) acc[i][j] += a[i] * bb[j];
    }
    __syncthreads();
  }
  #pragma unroll
  for (int i = 0; i < 4; ++i) {
    int r = row0 + ty * 4 + i;
    int bb_ = r >> 10, s = r & 1023;
    #pragma unroll
    for (int j = 0; j < 4; ++j) {
      int c = col0 + tx * 4 + j;
      int hh = c >> 6, dd = c & 63;
      outb[(((bb_ * NH + hh) * SEQ) + s) * DK + dd] = acc[i][j] + bias[c];
    }
  }
}

// ---- fused scores -> thermo sampling -> normalized weighted V sum ----
__global__ __launch_bounds__(256)
void fused_attn(const float* __restrict__ Qb, const float* __restrict__ Kb,
                const float* __restrict__ Vb, float* __restrict__ attn2) {
  const int b = blockIdx.z, h = blockIdx.y;
  const int q0 = blockIdx.x * 16;
  const int bh = b * NH + h;
  __shared__ float Qs[16][DK];
  __shared__ float KVs[64][DK + 1];
  __shared__ float Ws[16][DK + 1];
  const int t = threadIdx.x;
  const int lane = t & 63;
  const int ty = t >> 6;

  {
    int idx = t * 4;
    int r = idx >> 6, c = idx & 63;
    *(float4*)&Qs[r][c] = *(const float4*)&Qb[((bh * SEQ) + q0 + r) * DK + c];
  }
  float acc[4] = {0.f, 0.f, 0.f, 0.f};
  uint32_t rc[4] = {0u, 0u, 0u, 0u};
  uint32_t jrow[4];
  #pragma unroll
  for (int i = 0; i < 4; ++i)
    jrow[i] = ((uint32_t)bh * SEQ + (uint32_t)(q0 + ty * 4 + i)) * SEQ;

  for (int kt = 0; kt < SEQ; kt += 64) {
    __syncthreads();                     // prev-iter attn reads done before KVs overwrite
    #pragma unroll
    for (int p = 0; p < 16; ++p) {       // stage K tile (64 x 64)
      int idx = t + p * 256;
      int r = idx >> 6, c = idx & 63;
      KVs[r][c] = Kb[((bh * SEQ) + kt + r) * DK + c];
    }
    __syncthreads();
    // scores: 4 q-rows x this lane's k column
    float sc0 = 0.f, sc1 = 0.f, sc2 = 0.f, sc3 = 0.f;
    #pragma unroll 8
    for (int dd = 0; dd < DK; ++dd) {
      float kv = KVs[lane][dd];
      sc0 += Qs[ty * 4 + 0][dd] * kv;
      sc1 += Qs[ty * 4 + 1][dd] * kv;
      sc2 += Qs[ty * 4 + 2][dd] * kv;
      sc3 += Qs[ty * 4 + 3][dd] * kv;
    }
    // u < p  <=>  (bits>>9) < ceil(p * 2^23)   (exact: u = m*2^-23)
    uint32_t T[4];
    {
      float scs[4] = {sc0, sc1, sc2, sc3};
      #pragma unroll
      for (int i = 0; i < 4; ++i) {
        float p = 1.0f / (1.0f + expf(-scs[i] * 0.125f));
        T[i] = (uint32_t)ceilf(p * 8388608.0f);
      }
    }
    uint32_t cnt0 = 0, cnt1 = 0, cnt2 = 0, cnt3 = 0;
    const uint32_t jc = (uint32_t)(kt + lane);
    #pragma unroll 1                       // keep I-cache small; 4-chain ILP inside
    for (int s = 0; s < NS; ++s) {
      uint32_t k0 = d_keys.a[s], k1 = d_keys.b[s];
      uint32_t bits;
      bits = draw_bits(k0, k1, jrow[0] + jc); cnt0 += ((bits >> 9) < T[0]);
      bits = draw_bits(k0, k1, jrow[1] + jc); cnt1 += ((bits >> 9) < T[1]);
      bits = draw_bits(k0, k1, jrow[2] + jc); cnt2 += ((bits >> 9) < T[2]);
      bits = draw_bits(k0, k1, jrow[3] + jc); cnt3 += ((bits >> 9) < T[3]);
    }
    Ws[ty * 4 + 0][lane] = (float)cnt0 * 0.03125f;
    Ws[ty * 4 + 1][lane] = (float)cnt1 * 0.03125f;
    Ws[ty * 4 + 2][lane] = (float)cnt2 * 0.03125f;
    Ws[ty * 4 + 3][lane] = (float)cnt3 * 0.03125f;
    rc[0] += cnt0; rc[1] += cnt1; rc[2] += cnt2; rc[3] += cnt3;
    __syncthreads();                     // Ws visible; K-tile reads done
    #pragma unroll
    for (int p = 0; p < 16; ++p) {       // stage V tile
      int idx = t + p * 256;
      int r = idx >> 6, c = idx & 63;
      KVs[r][c] = Vb[((bh * SEQ) + kt + r) * DK + c];
    }
    __syncthreads();
    #pragma unroll 8
    for (int kk = 0; kk < 64; ++kk) {
      float vv = KVs[kk][lane];
      acc[0] += Ws[ty * 4 + 0][kk] * vv;
      acc[1] += Ws[ty * 4 + 1][kk] * vv;
      acc[2] += Ws[ty * 4 + 2][kk] * vv;
      acc[3] += Ws[ty * 4 + 3][kk] * vv;
    }
  }
  // integer row totals across the wave's 64 k-columns (deterministic)
  #pragma unroll
  for (int i = 0; i < 4; ++i) {
    uint32_t v = rc[i];
    #pragma unroll
    for (int off = 32; off >= 1; off >>= 1) v += (uint32_t)__shfl_xor((int)v, off, 64);
    rc[i] = v;
  }
  #pragma unroll
  for (int i = 0; i < 4; ++i) {
    int q = q0 + ty * 4 + i;
    float o = (rc[i] > 0u) ? acc[i] * (32.0f / (float)rc[i]) : 0.0f;  // rowsum = rc/32
    attn2[((b * SEQ) + q) * DM + h * DK + lane] = o;
  }
}

// ---- output projection: out[r,e] = A[r,:] . Wo[e,:] + bo[e] ----
__global__ __launch_bounds__(256)
void gemm_out(const float* __restrict__ A, const float* __restrict__ Wo,
              const float* __restrict__ bo, float* __restrict__ out) {
  const int row0 = blockIdx.y * 64;
  const int col0 = blockIdx.x * 64;
  __shared__ float As[64][17];
  __shared__ float Bs[16][65];
  const int t = threadIdx.x;
  const int tx = t & 15, ty = t >> 4;
  float acc[4][4] = {};
  for (int k0 = 0; k0 < DM; k0 += 16) {
    #pragma unroll
    for (int i = 0; i < 4; ++i) {
      int idx = t + i * 256;
      int ar = idx >> 4, ac = idx & 15;
      As[ar][ac] = A[(row0 + ar) * DM + k0 + ac];
      int kk = idx & 15, c = idx >> 4;
      Bs[kk][c] = Wo[(col0 + c) * DM + k0 + kk];
    }
    __syncthreads();
    #pragma unroll
    for (int kk = 0; kk < 16; ++kk) {
      float a[4], bb[4];
      #pragma unroll
      for (int i = 0; i < 4; ++i) a[i] = As[ty * 4 + i][kk];
      #pragma unroll
      for (int j = 0; j < 4; ++j) bb[j] = Bs[kk][tx * 4 + j];
      #pragma unroll
      for (int i = 0; i < 4; ++i)
        #pragma unroll
        for (int j = 0; j < 4; ++j) acc[i][j] += a[i] * bb[j];
    }
    __syncthreads();
  }
  #pragma unroll
  for (int i = 0; i < 4; ++i)
    #pragma unroll
    for (int j = 0; j < 4; ++j)
      out[(row0 + ty * 4 + i) * DM + col0 + tx * 4 + j] =
          acc[i][j] + bo[col0 + tx * 4 + j];
}

extern "C" void kernel_launch(void* const* d_in, const int* in_sizes, int n_in,
                              void* d_out, int out_size, void* d_ws, size_t ws_size,
                              hipStream_t stream) {
  const float* x  = (const float*)d_in[0];
  const float* Wq = (const float*)d_in[1];
  const float* bq = (const float*)d_in[2];
  const float* Wk = (const float*)d_in[3];
  const float* bk = (const float*)d_in[4];
  const float* Wv = (const float*)d_in[5];
  const float* bv = (const float*)d_in[6];
  const float* Wo = (const float*)d_in[7];
  const float* bo = (const float*)d_in[8];

  const size_t nQ = (size_t)2 * NH * SEQ * DK;  // 1,572,864 floats each
  float* Qb    = (float*)d_ws;
  float* Kb    = Qb + nQ;
  float* Vb    = Kb + nQ;
  float* attn2 = Vb + nQ;
  if (ws_size < 4 * nQ * sizeof(float)) return;

  gemm_qkv<<<dim3(DM / 64, 2 * SEQ / 64, 3), 256, 0, stream>>>(
      x, Wq, bq, Wk, bk, Wv, bv, Qb, Kb, Vb);
  fused_attn<<<dim3(SEQ / 16, NH, 2), 256, 0, stream>>>(Qb, Kb, Vb, attn2);
  gemm_out<<<dim3(DM / 64, 2 * SEQ / 64), 256, 0, stream>>>(attn2, Wo, bo, (float*)d_out);
}

// Round 2
// 1754.580 us; speedup vs baseline: 1.0118x; 1.0118x over previous
//
#include <hip/hip_runtime.h>
#include <stdint.h>

#define NH  12
#define SEQ 1024
#define DM  768
#define DK  64
#define NS  32

// ---- threefry2x32-20, exact JAX round/key-injection schedule (host constexpr) ----
#define TF1(r) { x0 += x1; x1 = (x1 << (r)) | (x1 >> (32 - (r))); x1 ^= x0; }
#define TF4(a,b,c,d) TF1(a) TF1(b) TF1(c) TF1(d)
#define TF_BODY(K0, K1) do { \
  uint32_t ks2_ = (K0) ^ (K1) ^ 0x1BD11BDAu; \
  x0 += (K0); x1 += (K1); \
  TF4(13,15,26,6) \
  x0 += (K1); x1 += ks2_ + 1u; \
  TF4(17,29,16,24) \
  x0 += ks2_; x1 += (K0) + 2u; \
  TF4(13,15,26,6) \
  x0 += (K0); x1 += (K1) + 3u; \
  TF4(17,29,16,24) \
  x0 += (K1); x1 += ks2_ + 4u; \
  TF4(13,15,26,6) \
  x0 += ks2_; x1 += (K0) + 5u; \
} while (0)

struct KeysT { uint32_t a[NS]; uint32_t b[NS]; };

constexpr KeysT make_keys() {
  KeysT K{};
  for (int s = 0; s < NS; ++s) {            // partitionable split: counter (0, s), key (0,42)
    uint32_t x0 = 0u, x1 = (uint32_t)s;
    TF_BODY(0u, 42u);
    K.a[s] = x0; K.b[s] = x1;
  }
  return K;
}

__constant__ KeysT d_keys = make_keys();

// ---- device threefry: hand-folded to ~64 VALU ops ----
// rotl as a single v_alignbit_b32
__device__ __forceinline__ uint32_t rotl1(uint32_t x, int r) {
  return __builtin_amdgcn_alignbit(x, x, 32 - r);
}
// plain round: 3 ops (add, alignbit, xor)
#define QR(r) { x0 += x1; x1 = rotl1(x1, (r)); x1 ^= x0; }

// Full 20-round threefry2x32 for counter (0, j), key schedule (k0,k1,ks2).
// Injections folded into the following round's add via v_add3 patterns.
// Verified step-by-step identical to TF_BODY with x0=0, x1=j.
__device__ __forceinline__ uint32_t tf_draw(uint32_t j, uint32_t k0, uint32_t k1,
                                            uint32_t ks2) {
  uint32_t x1 = j + k1;                 // inject0 on x1
  uint32_t x0 = x1 + k0;                // inject0 on x0 + round1 add, folded
  x1 = rotl1(x1, 13); x1 ^= x0;         // round 1 rest
  QR(15) QR(26) QR(6)                   // rounds 2-4
  x1 = x1 + ks2 + 1u;                   // inject1 (v_add3: v,s,imm)
  x0 = x0 + k1 + x1;                    // inject1 + round5 add (v_add3)
  x1 = rotl1(x1, 17); x1 ^= x0;         // round 5 rest
  QR(29) QR(16) QR(24)                  // rounds 6-8
  x1 = x1 + k0 + 2u;                    // inject2
  x0 = x0 + ks2 + x1;                   // inject2 + round9 add
  x1 = rotl1(x1, 13); x1 ^= x0;
  QR(15) QR(26) QR(6)                   // rounds 10-12
  x1 = x1 + k1 + 3u;                    // inject3
  x0 = x0 + k0 + x1;                    // inject3 + round13 add
  x1 = rotl1(x1, 17); x1 ^= x0;
  QR(29) QR(16) QR(24)                  // rounds 14-16
  x1 = x1 + ks2 + 4u;                   // inject4
  x0 = x0 + k1 + x1;                    // inject4 + round17 add
  x1 = rotl1(x1, 13); x1 ^= x0;
  QR(15) QR(26) QR(6)                   // rounds 18-20
  return (x0 + ks2) ^ (x1 + k0 + 5u);   // inject5 + xor-fold (partitionable bits)
}

// ---- QKV projection: out[r,c] = x[r,:] . W[c,:] + bias[c], scattered to [b,h,s,dk] ----
__global__ __launch_bounds__(256)
void gemm_qkv(const float* __restrict__ x,
              const float* __restrict__ Wq, const float* __restrict__ bq,
              const float* __restrict__ Wk, const float* __restrict__ bk,
              const float* __restrict__ Wv, const float* __restrict__ bv,
              float* __restrict__ Qb, float* __restrict__ Kb, float* __restrict__ Vb) {
  const int z = blockIdx.z;
  const float* W    = (z == 0) ? Wq : (z == 1) ? Wk : Wv;
  const float* bias = (z == 0) ? bq : (z == 1) ? bk : bv;
  float* outb       = (z == 0) ? Qb : (z == 1) ? Kb : Vb;
  const int row0 = blockIdx.y * 64;
  const int col0 = blockIdx.x * 64;
  __shared__ float As[64][17];
  __shared__ float Bs[16][65];
  const int t = threadIdx.x;
  const int tx = t & 15, ty = t >> 4;
  float acc[4][4] = {};
  for (int k0 = 0; k0 < DM; k0 += 16) {
    #pragma unroll
    for (int i = 0; i < 4; ++i) {
      int idx = t + i * 256;
      int ar = idx >> 4, ac = idx & 15;
      As[ar][ac] = x[(row0 + ar) * DM + k0 + ac];
      int kk = idx & 15, c = idx >> 4;
      Bs[kk][c] = W[(col0 + c) * DM + k0 + kk];
    }
    __syncthreads();
    #pragma unroll
    for (int kk = 0; kk < 16; ++kk) {
      float a[4], bb[4];
      #pragma unroll
      for (int i = 0; i < 4; ++i) a[i] = As[ty * 4 + i][kk];
      #pragma unroll
      for (int j = 0; j < 4; ++j) bb[j] = Bs[kk][tx * 4 + j];
      #pragma unroll
      for (int i = 0; i < 4; ++i)
        #pragma unroll
        for (int j = 0; j < 4; ++j) acc[i][j] += a[i] * bb[j];
    }
    __syncthreads();
  }
  #pragma unroll
  for (int i = 0; i < 4; ++i) {
    int r = row0 + ty * 4 + i;
    int bb_ = r >> 10, s = r & 1023;
    #pragma unroll
    for (int j = 0; j < 4; ++j) {
      int c = col0 + tx * 4 + j;
      int hh = c >> 6, dd = c & 63;
      outb[(((bb_ * NH + hh) * SEQ) + s) * DK + dd] = acc[i][j] + bias[c];
    }
  }
}

// ---- fused scores -> thermo sampling -> normalized weighted V sum ----
__global__ __launch_bounds__(256)
void fused_attn(const float* __restrict__ Qb, const float* __restrict__ Kb,
                const float* __restrict__ Vb, float* __restrict__ attn2) {
  const int b = blockIdx.z, h = blockIdx.y;
  const int q0 = blockIdx.x * 16;
  const int bh = b * NH + h;
  __shared__ float Qs[16][DK];
  __shared__ float KVs[64][DK + 1];
  __shared__ float Ws[16][DK + 1];
  const int t = threadIdx.x;
  const int lane = t & 63;
  const int ty = t >> 6;

  {
    int idx = t * 4;
    int r = idx >> 6, c = idx & 63;
    *(float4*)&Qs[r][c] = *(const float4*)&Qb[((bh * SEQ) + q0 + r) * DK + c];
  }
  float acc[4] = {0.f, 0.f, 0.f, 0.f};
  uint32_t rc[4] = {0u, 0u, 0u, 0u};
  uint32_t jrow[4];
  #pragma unroll
  for (int i = 0; i < 4; ++i)
    jrow[i] = ((uint32_t)bh * SEQ + (uint32_t)(q0 + ty * 4 + i)) * SEQ;

  for (int kt = 0; kt < SEQ; kt += 64) {
    __syncthreads();                     // prev-iter attn reads done before KVs overwrite
    #pragma unroll
    for (int p = 0; p < 16; ++p) {       // stage K tile (64 x 64)
      int idx = t + p * 256;
      int r = idx >> 6, c = idx & 63;
      KVs[r][c] = Kb[((bh * SEQ) + kt + r) * DK + c];
    }
    __syncthreads();
    // scores: 4 q-rows x this lane's k column
    float sc0 = 0.f, sc1 = 0.f, sc2 = 0.f, sc3 = 0.f;
    #pragma unroll 8
    for (int dd = 0; dd < DK; ++dd) {
      float kv = KVs[lane][dd];
      sc0 += Qs[ty * 4 + 0][dd] * kv;
      sc1 += Qs[ty * 4 + 1][dd] * kv;
      sc2 += Qs[ty * 4 + 2][dd] * kv;
      sc3 += Qs[ty * 4 + 3][dd] * kv;
    }
    // u < p  <=>  (bits>>9) < ceil(p * 2^23)   (exact: u = m*2^-23)
    uint32_t T0, T1, T2, T3;
    {
      T0 = (uint32_t)ceilf(8388608.0f / (1.0f + expf(-sc0 * 0.125f)));
      T1 = (uint32_t)ceilf(8388608.0f / (1.0f + expf(-sc1 * 0.125f)));
      T2 = (uint32_t)ceilf(8388608.0f / (1.0f + expf(-sc2 * 0.125f)));
      T3 = (uint32_t)ceilf(8388608.0f / (1.0f + expf(-sc3 * 0.125f)));
    }
    // hoist per-tile counters
    const uint32_t jc = (uint32_t)(kt + lane);
    const uint32_t jq0 = jrow[0] + jc;
    const uint32_t jq1 = jrow[1] + jc;
    const uint32_t jq2 = jrow[2] + jc;
    const uint32_t jq3 = jrow[3] + jc;
    uint32_t cnt0 = 0, cnt1 = 0, cnt2 = 0, cnt3 = 0;
    #pragma unroll 2
    for (int s = 0; s < NS; ++s) {
      const uint32_t k0 = d_keys.a[s], k1 = d_keys.b[s];
      const uint32_t ks2 = k0 ^ k1 ^ 0x1BD11BDAu;   // SALU
      uint32_t b0 = tf_draw(jq0, k0, k1, ks2);
      uint32_t b1 = tf_draw(jq1, k0, k1, ks2);
      uint32_t b2 = tf_draw(jq2, k0, k1, ks2);
      uint32_t b3 = tf_draw(jq3, k0, k1, ks2);
      cnt0 += ((b0 >> 9) < T0);
      cnt1 += ((b1 >> 9) < T1);
      cnt2 += ((b2 >> 9) < T2);
      cnt3 += ((b3 >> 9) < T3);
    }
    Ws[ty * 4 + 0][lane] = (float)cnt0 * 0.03125f;
    Ws[ty * 4 + 1][lane] = (float)cnt1 * 0.03125f;
    Ws[ty * 4 + 2][lane] = (float)cnt2 * 0.03125f;
    Ws[ty * 4 + 3][lane] = (float)cnt3 * 0.03125f;
    rc[0] += cnt0; rc[1] += cnt1; rc[2] += cnt2; rc[3] += cnt3;
    __syncthreads();                     // Ws visible; K-tile reads done
    #pragma unroll
    for (int p = 0; p < 16; ++p) {       // stage V tile
      int idx = t + p * 256;
      int r = idx >> 6, c = idx & 63;
      KVs[r][c] = Vb[((bh * SEQ) + kt + r) * DK + c];
    }
    __syncthreads();
    #pragma unroll 8
    for (int kk = 0; kk < 64; ++kk) {
      float vv = KVs[kk][lane];
      acc[0] += Ws[ty * 4 + 0][kk] * vv;
      acc[1] += Ws[ty * 4 + 1][kk] * vv;
      acc[2] += Ws[ty * 4 + 2][kk] * vv;
      acc[3] += Ws[ty * 4 + 3][kk] * vv;
    }
  }
  // integer row totals across the wave's 64 k-columns (deterministic)
  #pragma unroll
  for (int i = 0; i < 4; ++i) {
    uint32_t v = rc[i];
    #pragma unroll
    for (int off = 32; off >= 1; off >>= 1) v += (uint32_t)__shfl_xor((int)v, off, 64);
    rc[i] = v;
  }
  #pragma unroll
  for (int i = 0; i < 4; ++i) {
    int q = q0 + ty * 4 + i;
    float o = (rc[i] > 0u) ? acc[i] * (32.0f / (float)rc[i]) : 0.0f;  // rowsum = rc/32
    attn2[((b * SEQ) + q) * DM + h * DK + lane] = o;
  }
}

// ---- output projection: out[r,e] = A[r,:] . Wo[e,:] + bo[e] ----
__global__ __launch_bounds__(256)
void gemm_out(const float* __restrict__ A, const float* __restrict__ Wo,
              const float* __restrict__ bo, float* __restrict__ out) {
  const int row0 = blockIdx.y * 64;
  const int col0 = blockIdx.x * 64;
  __shared__ float As[64][17];
  __shared__ float Bs[16][65];
  const int t = threadIdx.x;
  const int tx = t & 15, ty = t >> 4;
  float acc[4][4] = {};
  for (int k0 = 0; k0 < DM; k0 += 16) {
    #pragma unroll
    for (int i = 0; i < 4; ++i) {
      int idx = t + i * 256;
      int ar = idx >> 4, ac = idx & 15;
      As[ar][ac] = A[(row0 + ar) * DM + k0 + ac];
      int kk = idx & 15, c = idx >> 4;
      Bs[kk][c] = Wo[(col0 + c) * DM + k0 + kk];
    }
    __syncthreads();
    #pragma unroll
    for (int kk = 0; kk < 16; ++kk) {
      float a[4], bb[4];
      #pragma unroll
      for (int i = 0; i < 4; ++i) a[i] = As[ty * 4 + i][kk];
      #pragma unroll
      for (int j = 0; j < 4; ++j) bb[j] = Bs[kk][tx * 4 + j];
      #pragma unroll
      for (int i = 0; i < 4; ++i)
        #pragma unroll
        for (int j = 0; j < 4; ++j) acc[i][j] += a[i] * bb[j];
    }
    __syncthreads();
  }
  #pragma unroll
  for (int i = 0; i < 4; ++i)
    #pragma unroll
    for (int j = 0; j < 4; ++j)
      out[(row0 + ty * 4 + i) * DM + col0 + tx * 4 + j] =
          acc[i][j] + bo[col0 + tx * 4 + j];
}

extern "C" void kernel_launch(void* const* d_in, const int* in_sizes, int n_in,
                              void* d_out, int out_size, void* d_ws, size_t ws_size,
                              hipStream_t stream) {
  const float* x  = (const float*)d_in[0];
  const float* Wq = (const float*)d_in[1];
  const float* bq = (const float*)d_in[2];
  const float* Wk = (const float*)d_in[3];
  const float* bk = (const float*)d_in[4];
  const float* Wv = (const float*)d_in[5];
  const float* bv = (const float*)d_in[6];
  const float* Wo = (const float*)d_in[7];
  const float* bo = (const float*)d_in[8];

  const size_t nQ = (size_t)2 * NH * SEQ * DK;  // 1,572,864 floats each
  float* Qb    = (float*)d_ws;
  float* Kb    = Qb + nQ;
  float* Vb    = Kb + nQ;
  float* attn2 = Vb + nQ;
  if (ws_size < 4 * nQ * sizeof(float)) return;

  gemm_qkv<<<dim3(DM / 64, 2 * SEQ / 64, 3), 256, 0, stream>>>(
      x, Wq, bq, Wk, bk, Wv, bv, Qb, Kb, Vb);
  fused_attn<<<dim3(SEQ / 16, NH, 2), 256, 0, stream>>>(Qb, Kb, Vb, attn2);
  gemm_out<<<dim3(DM / 64, 2 * SEQ / 64), 256, 0, stream>>>(attn2, Wo, bo, (float*)d_out);
}

// Round 3
// 1719.964 us; speedup vs baseline: 1.0322x; 1.0201x over previous
//
#include <hip/hip_runtime.h>
#include <stdint.h>

#define NH  12
#define SEQ 1024
#define DM  768
#define DK  64
#define NS  32

// ---- threefry2x32-20, exact JAX round/key-injection schedule (host constexpr) ----
#define TF1(r) { x0 += x1; x1 = (x1 << (r)) | (x1 >> (32 - (r))); x1 ^= x0; }
#define TF4(a,b,c,d) TF1(a) TF1(b) TF1(c) TF1(d)
#define TF_BODY(K0, K1) do { \
  uint32_t ks2_ = (K0) ^ (K1) ^ 0x1BD11BDAu; \
  x0 += (K0); x1 += (K1); \
  TF4(13,15,26,6) \
  x0 += (K1); x1 += ks2_ + 1u; \
  TF4(17,29,16,24) \
  x0 += ks2_; x1 += (K0) + 2u; \
  TF4(13,15,26,6) \
  x0 += (K0); x1 += (K1) + 3u; \
  TF4(17,29,16,24) \
  x0 += (K1); x1 += ks2_ + 4u; \
  TF4(13,15,26,6) \
  x0 += ks2_; x1 += (K0) + 5u; \
} while (0)

struct KeysT { uint32_t ab[NS][2]; };   // interleaved (k0,k1) -> one s_load_dwordx2

constexpr KeysT make_keys() {
  KeysT K{};
  for (int s = 0; s < NS; ++s) {        // partitionable split: counter (0, s), key (0,42)
    uint32_t x0 = 0u, x1 = (uint32_t)s;
    TF_BODY(0u, 42u);
    K.ab[s][0] = x0; K.ab[s][1] = x1;
  }
  return K;
}

__constant__ KeysT d_keys = make_keys();

// rotl as a single v_alignbit_b32
__device__ __forceinline__ uint32_t rotl1(uint32_t x, int r) {
  return __builtin_amdgcn_alignbit(x, x, 32 - r);
}
#define QR(r) { x0 += x1; x1 = rotl1(x1, (r)); x1 ^= x0; }

// Full 20-round threefry2x32 for counter (0, j), key schedule (k0,k1,ks2).
// Injections folded into the following round's add. Bit-identical to TF_BODY.
__device__ __forceinline__ uint32_t tf_draw(uint32_t j, uint32_t k0, uint32_t k1,
                                            uint32_t ks2) {
  uint32_t x1 = j + k1;                 // inject0 on x1
  uint32_t x0 = x1 + k0;                // inject0 on x0 + round1 add, folded
  x1 = rotl1(x1, 13); x1 ^= x0;         // round 1 rest
  QR(15) QR(26) QR(6)                   // rounds 2-4
  x1 = x1 + ks2 + 1u;                   // inject1
  x0 = x0 + k1 + x1;                    // inject1 + round5 add
  x1 = rotl1(x1, 17); x1 ^= x0;
  QR(29) QR(16) QR(24)                  // rounds 6-8
  x1 = x1 + k0 + 2u;                    // inject2
  x0 = x0 + ks2 + x1;                   // inject2 + round9 add
  x1 = rotl1(x1, 13); x1 ^= x0;
  QR(15) QR(26) QR(6)                   // rounds 10-12
  x1 = x1 + k1 + 3u;                    // inject3
  x0 = x0 + k0 + x1;                    // inject3 + round13 add
  x1 = rotl1(x1, 17); x1 ^= x0;
  QR(29) QR(16) QR(24)                  // rounds 14-16
  x1 = x1 + ks2 + 4u;                   // inject4
  x0 = x0 + k1 + x1;                    // inject4 + round17 add
  x1 = rotl1(x1, 13); x1 ^= x0;
  QR(15) QR(26) QR(6)                   // rounds 18-20
  return (x0 + ks2) ^ (x1 + k0 + 5u);   // inject5 + xor-fold (partitionable bits)
}

// ---- QKV projection: out[r,c] = x[r,:] . W[c,:] + bias[c], scattered to [b,h,s,dk] ----
__global__ __launch_bounds__(256)
void gemm_qkv(const float* __restrict__ x,
              const float* __restrict__ Wq, const float* __restrict__ bq,
              const float* __restrict__ Wk, const float* __restrict__ bk,
              const float* __restrict__ Wv, const float* __restrict__ bv,
              float* __restrict__ Qb, float* __restrict__ Kb, float* __restrict__ Vb) {
  const int z = blockIdx.z;
  const float* W    = (z == 0) ? Wq : (z == 1) ? Wk : Wv;
  const float* bias = (z == 0) ? bq : (z == 1) ? bk : bv;
  float* outb       = (z == 0) ? Qb : (z == 1) ? Kb : Vb;
  const int row0 = blockIdx.y * 64;
  const int col0 = blockIdx.x * 64;
  __shared__ float As[64][17];
  __shared__ float Bs[16][65];
  const int t = threadIdx.x;
  const int tx = t & 15, ty = t >> 4;
  float acc[4][4] = {};
  for (int k0 = 0; k0 < DM; k0 += 16) {
    #pragma unroll
    for (int i = 0; i < 4; ++i) {
      int idx = t + i * 256;
      int ar = idx >> 4, ac = idx & 15;
      As[ar][ac] = x[(row0 + ar) * DM + k0 + ac];
      int kk = idx & 15, c = idx >> 4;
      Bs[kk][c] = W[(col0 + c) * DM + k0 + kk];
    }
    __syncthreads();
    #pragma unroll
    for (int kk = 0; kk < 16; ++kk) {
      float a[4], bb[4];
      #pragma unroll
      for (int i = 0; i < 4; ++i) a[i] = As[ty * 4 + i][kk];
      #pragma unroll
      for (int j = 0; j < 4; ++j) bb[j] = Bs[kk][tx * 4 + j];
      #pragma unroll
      for (int i = 0; i < 4; ++i)
        #pragma unroll
        for (int j = 0; j < 4; ++j) acc[i][j] += a[i] * bb[j];
    }
    __syncthreads();
  }
  #pragma unroll
  for (int i = 0; i < 4; ++i) {
    int r = row0 + ty * 4 + i;
    int bb_ = r >> 10, s = r & 1023;
    #pragma unroll
    for (int j = 0; j < 4; ++j) {
      int c = col0 + tx * 4 + j;
      int hh = c >> 6, dd = c & 63;
      outb[(((bb_ * NH + hh) * SEQ) + s) * DK + dd] = acc[i][j] + bias[c];
    }
  }
}

// ---- fused scores -> thermo sampling -> normalized weighted V sum ----
__global__ __launch_bounds__(256)
void fused_attn(const float* __restrict__ Qb, const float* __restrict__ Kb,
                const float* __restrict__ Vb, float* __restrict__ attn2) {
  const int b = blockIdx.z, h = blockIdx.y;
  const int q0 = blockIdx.x * 16;
  const int bh = b * NH + h;
  __shared__ float Qs[16][DK];
  __shared__ float KVs[64][DK + 1];
  __shared__ float Ws[16][DK + 1];
  const int t = threadIdx.x;
  const int lane = t & 63;
  const int ty = t >> 6;

  {
    int idx = t * 4;
    int r = idx >> 6, c = idx & 63;
    *(float4*)&Qs[r][c] = *(const float4*)&Qb[((bh * SEQ) + q0 + r) * DK + c];
  }
  float acc[4] = {0.f, 0.f, 0.f, 0.f};
  uint32_t rc[4] = {0u, 0u, 0u, 0u};
  uint32_t jrow[4];
  #pragma unroll
  for (int i = 0; i < 4; ++i)
    jrow[i] = ((uint32_t)bh * SEQ + (uint32_t)(q0 + ty * 4 + i)) * SEQ;

  for (int kt = 0; kt < SEQ; kt += 64) {
    __syncthreads();                     // prev-iter attn reads done before KVs overwrite
    #pragma unroll
    for (int p = 0; p < 16; ++p) {       // stage K tile (64 x 64)
      int idx = t + p * 256;
      int r = idx >> 6, c = idx & 63;
      KVs[r][c] = Kb[((bh * SEQ) + kt + r) * DK + c];
    }
    __syncthreads();
    // scores: 4 q-rows x this lane's k column
    float sc0 = 0.f, sc1 = 0.f, sc2 = 0.f, sc3 = 0.f;
    #pragma unroll 8
    for (int dd = 0; dd < DK; ++dd) {
      float kv = KVs[lane][dd];
      sc0 += Qs[ty * 4 + 0][dd] * kv;
      sc1 += Qs[ty * 4 + 1][dd] * kv;
      sc2 += Qs[ty * 4 + 2][dd] * kv;
      sc3 += Qs[ty * 4 + 3][dd] * kv;
    }
    // u < p  <=>  bits < (ceil(p * 2^23) << 9)   (exact; shift hoisted off the draw path)
    uint32_t T9_0, T9_1, T9_2, T9_3;
    {
      T9_0 = ((uint32_t)ceilf(8388608.0f / (1.0f + expf(-sc0 * 0.125f)))) << 9;
      T9_1 = ((uint32_t)ceilf(8388608.0f / (1.0f + expf(-sc1 * 0.125f)))) << 9;
      T9_2 = ((uint32_t)ceilf(8388608.0f / (1.0f + expf(-sc2 * 0.125f)))) << 9;
      T9_3 = ((uint32_t)ceilf(8388608.0f / (1.0f + expf(-sc3 * 0.125f)))) << 9;
    }
    // hoist per-tile counters
    const uint32_t jc = (uint32_t)(kt + lane);
    const uint32_t jq0 = jrow[0] + jc;
    const uint32_t jq1 = jrow[1] + jc;
    const uint32_t jq2 = jrow[2] + jc;
    const uint32_t jq3 = jrow[3] + jc;
    uint32_t cnt0 = 0, cnt1 = 0, cnt2 = 0, cnt3 = 0;
    #pragma unroll 4
    for (int s = 0; s < NS; ++s) {
      const uint32_t k0 = d_keys.ab[s][0], k1 = d_keys.ab[s][1];
      const uint32_t ks2 = k0 ^ k1 ^ 0x1BD11BDAu;   // SALU
      uint32_t b0 = tf_draw(jq0, k0, k1, ks2);
      uint32_t b1 = tf_draw(jq1, k0, k1, ks2);
      uint32_t b2 = tf_draw(jq2, k0, k1, ks2);
      uint32_t b3 = tf_draw(jq3, k0, k1, ks2);
      cnt0 += (b0 < T9_0);
      cnt1 += (b1 < T9_1);
      cnt2 += (b2 < T9_2);
      cnt3 += (b3 < T9_3);
    }
    Ws[ty * 4 + 0][lane] = (float)cnt0 * 0.03125f;
    Ws[ty * 4 + 1][lane] = (float)cnt1 * 0.03125f;
    Ws[ty * 4 + 2][lane] = (float)cnt2 * 0.03125f;
    Ws[ty * 4 + 3][lane] = (float)cnt3 * 0.03125f;
    rc[0] += cnt0; rc[1] += cnt1; rc[2] += cnt2; rc[3] += cnt3;
    __syncthreads();                     // Ws visible; K-tile reads done
    #pragma unroll
    for (int p = 0; p < 16; ++p) {       // stage V tile
      int idx = t + p * 256;
      int r = idx >> 6, c = idx & 63;
      KVs[r][c] = Vb[((bh * SEQ) + kt + r) * DK + c];
    }
    __syncthreads();
    #pragma unroll 8
    for (int kk = 0; kk < 64; ++kk) {
      float vv = KVs[kk][lane];
      acc[0] += Ws[ty * 4 + 0][kk] * vv;
      acc[1] += Ws[ty * 4 + 1][kk] * vv;
      acc[2] += Ws[ty * 4 + 2][kk] * vv;
      acc[3] += Ws[ty * 4 + 3][kk] * vv;
    }
  }
  // integer row totals across the wave's 64 k-columns (deterministic)
  #pragma unroll
  for (int i = 0; i < 4; ++i) {
    uint32_t v = rc[i];
    #pragma unroll
    for (int off = 32; off >= 1; off >>= 1) v += (uint32_t)__shfl_xor((int)v, off, 64);
    rc[i] = v;
  }
  #pragma unroll
  for (int i = 0; i < 4; ++i) {
    int q = q0 + ty * 4 + i;
    float o = (rc[i] > 0u) ? acc[i] * (32.0f / (float)rc[i]) : 0.0f;  // rowsum = rc/32
    attn2[((b * SEQ) + q) * DM + h * DK + lane] = o;
  }
}

// ---- output projection: out[r,e] = A[r,:] . Wo[e,:] + bo[e] ----
__global__ __launch_bounds__(256)
void gemm_out(const float* __restrict__ A, const float* __restrict__ Wo,
              const float* __restrict__ bo, float* __restrict__ out) {
  const int row0 = blockIdx.y * 64;
  const int col0 = blockIdx.x * 64;
  __shared__ float As[64][17];
  __shared__ float Bs[16][65];
  const int t = threadIdx.x;
  const int tx = t & 15, ty = t >> 4;
  float acc[4][4] = {};
  for (int k0 = 0; k0 < DM; k0 += 16) {
    #pragma unroll
    for (int i = 0; i < 4; ++i) {
      int idx = t + i * 256;
      int ar = idx >> 4, ac = idx & 15;
      As[ar][ac] = A[(row0 + ar) * DM + k0 + ac];
      int kk = idx & 15, c = idx >> 4;
      Bs[kk][c] = Wo[(col0 + c) * DM + k0 + kk];
    }
    __syncthreads();
    #pragma unroll
    for (int kk = 0; kk < 16; ++kk) {
      float a[4], bb[4];
      #pragma unroll
      for (int i = 0; i < 4; ++i) a[i] = As[ty * 4 + i][kk];
      #pragma unroll
      for (int j = 0; j < 4; ++j) bb[j] = Bs[kk][tx * 4 + j];
      #pragma unroll
      for (int i = 0; i < 4; ++i)
        #pragma unroll
        for (int j = 0; j < 4; ++j) acc[i][j] += a[i] * bb[j];
    }
    __syncthreads();
  }
  #pragma unroll
  for (int i = 0; i < 4; ++i)
    #pragma unroll
    for (int j = 0; j < 4; ++j)
      out[(row0 + ty * 4 + i) * DM + col0 + tx * 4 + j] =
          acc[i][j] + bo[col0 + tx * 4 + j];
}

extern "C" void kernel_launch(void* const* d_in, const int* in_sizes, int n_in,
                              void* d_out, int out_size, void* d_ws, size_t ws_size,
                              hipStream_t stream) {
  const float* x  = (const float*)d_in[0];
  const float* Wq = (const float*)d_in[1];
  const float* bq = (const float*)d_in[2];
  const float* Wk = (const float*)d_in[3];
  const float* bk = (const float*)d_in[4];
  const float* Wv = (const float*)d_in[5];
  const float* bv = (const float*)d_in[6];
  const float* Wo = (const float*)d_in[7];
  const float* bo = (const float*)d_in[8];

  const size_t nQ = (size_t)2 * NH * SEQ * DK;  // 1,572,864 floats each
  float* Qb    = (float*)d_ws;
  float* Kb    = Qb + nQ;
  float* Vb    = Kb + nQ;
  float* attn2 = Vb + nQ;
  if (ws_size < 4 * nQ * sizeof(float)) return;

  gemm_qkv<<<dim3(DM / 64, 2 * SEQ / 64, 3), 256, 0, stream>>>(
      x, Wq, bq, Wk, bk, Wv, bv, Qb, Kb, Vb);
  fused_attn<<<dim3(SEQ / 16, NH, 2), 256, 0, stream>>>(Qb, Kb, Vb, attn2);
  gemm_out<<<dim3(DM / 64, 2 * SEQ / 64), 256, 0, stream>>>(attn2, Wo, bo, (float*)d_out);
}